// Round 6
// baseline (343.681 us; speedup 1.0000x reference)
//
#include <hip/hip_runtime.h>
#include <hip/hip_bf16.h>

// B=4096, T=200, D=64, H=32 attention pooling with score MLP.
// score(b,t) = W2 . sigmoid( qa[b] + k_t @ Wk ),  Wk = W1b - W1c   (b2 softmax-invariant)
// qa[b][j]  = b1[j] + q_b @ wsum[:,j],  wsum = W1a + W1c  (precomputed f32)
// Fixed-offset softmax: w_t = 2^((s_t-16)*log2e); masked -> 0.
//
// R10 = MEASUREMENT ROUND. Five structures all gave total ~300-310; the only
// invariant is the gather shape (each wave-load touches 32 scattered lines).
// This round launches TWO attn kernels back-to-back:
//   1) attn_pool2 (EXPERIMENTAL): per-tile keys staged via global_load_lds
//      (16 contiguous lines/instr), wave-private double-buffered LDS slabs,
//      counted s_waitcnt vmcnt(4), XOR-swizzled granules (source-side permute +
//      same involution on ds_read, per rule 21). Downstream identical to R9.
//   2) attn_pool (VERIFIED R9 path): runs LAST, writes final out -> correctness
//      pinned to the proven kernel no matter what attn2 produces.
// total X  =>  attn2 duration = X - 299.8 (floor + attn_R9 cancel).

#define B 4096
#define T 200
#define D 64
#define H 32
#define LOG2E 1.44269504088896340736f
#define SOFF 16.0f
#define NTILE 13

typedef __attribute__((ext_vector_type(8))) short short8;   // 8 bf16 (MFMA A/B frag)
typedef __attribute__((ext_vector_type(4))) float f32x4;    // MFMA C/D frag

// ws float layout:
//   [0, 2048)       wsum[64][32] = W1a + W1c   (f32)
//   [2048, 3072)    wkf: 2048 bf16 B-fragments (1024 floats)

__global__ __launch_bounds__(256) void prep_kernel(
        const float* __restrict__ W1,     // [192,32]
        float*       __restrict__ ws)
{
    int n = blockIdx.x * 256 + threadIdx.x;
    if (blockIdx.x < 8) {                  // wsum = W1a + W1c
        int k = n >> 5;
        int j = n & 31;
        ws[n] = W1[k * H + j] + W1[(128 + k) * H + j];
    } else {                               // wkf B-fragments (layout verified R3/R4)
        int m = n - 2048;                  // 0..2047
        int e  = m & 7;
        int l  = (m >> 3) & 63;
        int fs = m >> 9;
        int ntile = fs >> 1, kstep = fs & 1;
        int k = kstep * 32 + (l >> 4) * 8 + e;
        int j = ntile * 16 + (l & 15);
        float v = W1[(64 + k) * H + j] - W1[(128 + k) * H + j];
        __hip_bfloat16 hv = __float2bfloat16(v);
        reinterpret_cast<unsigned short*>(ws + 2048)[m] =
            __builtin_bit_cast(unsigned short, hv);
    }
}

__device__ __forceinline__ unsigned short bf16u(float x) {
    __hip_bfloat16 h = __float2bfloat16(x);
    return __builtin_bit_cast(unsigned short, h);
}

__device__ __forceinline__ void gld16(const float* g, float* l) {
    __builtin_amdgcn_global_load_lds(
        (const __attribute__((address_space(1))) void*)g,
        (__attribute__((address_space(3))) void*)l, 16, 0, 0);
}

// ---------------- EXPERIMENTAL: contiguous-line staged loads ----------------
__global__ __launch_bounds__(256) void attn_pool2_kernel(
        const float* __restrict__ keys,   // [B,T,D] fp32
        const int*   __restrict__ mask,   // [B,T]
        const unsigned short* __restrict__ wkf,
        const float* __restrict__ wsum,   // [64][32] f32
        const float* __restrict__ b1,     // [32]
        const float* __restrict__ W2,     // [32]
        const float* __restrict__ query,  // [B,1,D]
        float*       __restrict__ out)    // [B,1,D]
{
    __shared__ float kslab[4][2][1024];   // [wave][dbuf][16 rows x 64 f], swizzled
    __shared__ float qsh[4][64];
    __shared__ float part[4][68];

    const int tid  = threadIdx.x;
    const int wv   = tid >> 6;
    const int lane = tid & 63;
    const int quad = lane >> 4;
    const int l15  = lane & 15;

    const int b = blockIdx.x;

    // ---- qa[b][0..31] in-wave, f32 (identical to R9) ----
    qsh[wv][lane] = query[(size_t)b * D + lane];
    const int jq = lane & 31;
    const int kh = lane >> 5;
    float qac0 = kh ? 0.0f : b1[jq];
    float qac1 = 0.0f;
    #pragma unroll
    for (int k0 = 0; k0 < 32; k0 += 2) {
        int k = kh * 32 + k0;
        qac0 = fmaf(qsh[wv][k],     wsum[k * H + jq],       qac0);
        qac1 = fmaf(qsh[wv][k + 1], wsum[(k + 1) * H + jq], qac1);
    }
    float qac = qac0 + qac1;
    qac += __shfl_xor(qac, 32, 64);
    const float qa0 = __shfl(qac, l15, 64);
    const float qa1 = __shfl(qac, 16 + l15, 64);

    const short8* wf = reinterpret_cast<const short8*>(wkf);
    short8 bf0 = wf[0 * 64 + lane];
    short8 bf1 = wf[1 * 64 + lane];
    short8 bf2 = wf[2 * 64 + lane];
    short8 bf3 = wf[3 * 64 + lane];
    const float w20 = W2[l15];
    const float w21 = W2[16 + l15];

    const float* kbase = keys + (size_t)b * (T * D);
    const int*   mrow  = mask + (size_t)b * T;

    // staging lane mapping: instr i covers rows i*4..i*4+3 (1KB contiguous)
    const int srow = lane >> 4;           // row-within-group
    const int sgi  = lane & 15;           // dest granule (16B) within row

    float acc[16];
    #pragma unroll
    for (int j = 0; j < 16; ++j) acc[j] = 0.0f;
    float dacc = 0.0f;

    const int ntl = (wv == 0) ? 4 : 3;    // tiles wv, wv+4, wv+8 (+12 for wv 0)

    // prologue: stage tile wv into buf0 (rows <= 63 < T, no clamp)
    int mA = mrow[wv * 16 + l15];
    {
        const int tb = wv * 16;
        #pragma unroll
        for (int i = 0; i < 4; ++i) {
            int rl = i * 4 + srow;
            int sg = (sgi & 8) | ((sgi ^ rl) & 7);      // source-side swizzle
            gld16(kbase + (size_t)(tb + rl) * D + sg * 4, &kslab[wv][0][i * 256]);
        }
    }

    int cb = 0;
    #pragma unroll 1
    for (int it = 0; it < ntl; ++it) {
        const int tile = wv + it * 4;

        // stage tile+4 (row-clamped, uniform code) + its mask
        int tn  = (tile + 4) * 16 + l15;
        int trn = (tn < T) ? tn : (T - 1);
        int mB  = mrow[trn];
        {
            const int tb = (tile + 4) * 16;
            #pragma unroll
            for (int i = 0; i < 4; ++i) {
                int rl = i * 4 + srow;
                int rg = tb + rl; if (rg >= T) rg = T - 1;
                int sg = (sgi & 8) | ((sgi ^ rl) & 7);
                gld16(kbase + (size_t)rg * D + sg * 4, &kslab[wv][cb ^ 1][i * 256]);
            }
        }

        // drain current buffer's stage (4 newest = next stage stays in flight)
        asm volatile("s_waitcnt vmcnt(4)" ::: "memory");
        __builtin_amdgcn_sched_barrier(0);

        // swizzled fragment reads: same involution as the staging permute
        const float* sl = kslab[wv][cb];
        const int x   = l15 & 7;
        const int gi0 = ((2 * quad)     ^ x) & 7;
        const int gi1 = ((2 * quad + 1) ^ x) & 7;
        float4 kA0 = *reinterpret_cast<const float4*>(&sl[l15 * 64 + gi0 * 4]);
        float4 kA1 = *reinterpret_cast<const float4*>(&sl[l15 * 64 + gi1 * 4]);
        float4 kA2 = *reinterpret_cast<const float4*>(&sl[l15 * 64 + 32 + gi0 * 4]);
        float4 kA3 = *reinterpret_cast<const float4*>(&sl[l15 * 64 + 32 + gi1 * 4]);

        // ---- downstream identical to R9 ----
        short8 a0, a1;
        a0[0] = (short)bf16u(kA0.x); a0[1] = (short)bf16u(kA0.y);
        a0[2] = (short)bf16u(kA0.z); a0[3] = (short)bf16u(kA0.w);
        a0[4] = (short)bf16u(kA1.x); a0[5] = (short)bf16u(kA1.y);
        a0[6] = (short)bf16u(kA1.z); a0[7] = (short)bf16u(kA1.w);
        a1[0] = (short)bf16u(kA2.x); a1[1] = (short)bf16u(kA2.y);
        a1[2] = (short)bf16u(kA2.z); a1[3] = (short)bf16u(kA2.w);
        a1[4] = (short)bf16u(kA3.x); a1[5] = (short)bf16u(kA3.y);
        a1[6] = (short)bf16u(kA3.z); a1[7] = (short)bf16u(kA3.w);

        f32x4 c0 = {0.f, 0.f, 0.f, 0.f};
        f32x4 c1 = {0.f, 0.f, 0.f, 0.f};
        c0 = __builtin_amdgcn_mfma_f32_16x16x32_bf16(a0, bf0, c0, 0, 0, 0);
        c0 = __builtin_amdgcn_mfma_f32_16x16x32_bf16(a1, bf1, c0, 0, 0, 0);
        c1 = __builtin_amdgcn_mfma_f32_16x16x32_bf16(a0, bf2, c1, 0, 0, 0);
        c1 = __builtin_amdgcn_mfma_f32_16x16x32_bf16(a1, bf3, c1, 0, 0, 0);

        float p[4];
        #pragma unroll
        for (int r = 0; r < 4; ++r) {
            float x0 = c0[r] + qa0;
            float x1 = c1[r] + qa1;
            float s0 = __builtin_amdgcn_rcpf(1.0f + exp2f(-x0 * LOG2E));
            float s1 = __builtin_amdgcn_rcpf(1.0f + exp2f(-x1 * LOG2E));
            p[r] = fmaf(s0, w20, s1 * w21);
        }
        #pragma unroll
        for (int r = 0; r < 4; ++r) {
            #pragma unroll
            for (int off = 1; off <= 8; off <<= 1)
                p[r] += __shfl_xor(p[r], off, 64);
        }
        const int addr = (l15 >> 2) << 6;
        int q0 = __builtin_amdgcn_ds_bpermute(addr, __builtin_bit_cast(int, p[0]));
        int q1 = __builtin_amdgcn_ds_bpermute(addr, __builtin_bit_cast(int, p[1]));
        int q2 = __builtin_amdgcn_ds_bpermute(addr, __builtin_bit_cast(int, p[2]));
        int q3 = __builtin_amdgcn_ds_bpermute(addr, __builtin_bit_cast(int, p[3]));
        const int rsel = l15 & 3;
        int s01 = (rsel & 1) ? q1 : q0;
        int s23 = (rsel & 1) ? q3 : q2;
        float st = __builtin_bit_cast(float, (rsel & 2) ? s23 : s01);

        const int t = tile * 16 + l15;
        const float w = ((t < T) && (mA != 0)) ? exp2f((st - SOFF) * LOG2E) : 0.0f;

        acc[0]  = fmaf(w, kA0.x, acc[0]);  acc[1]  = fmaf(w, kA0.y, acc[1]);
        acc[2]  = fmaf(w, kA0.z, acc[2]);  acc[3]  = fmaf(w, kA0.w, acc[3]);
        acc[4]  = fmaf(w, kA1.x, acc[4]);  acc[5]  = fmaf(w, kA1.y, acc[5]);
        acc[6]  = fmaf(w, kA1.z, acc[6]);  acc[7]  = fmaf(w, kA1.w, acc[7]);
        acc[8]  = fmaf(w, kA2.x, acc[8]);  acc[9]  = fmaf(w, kA2.y, acc[9]);
        acc[10] = fmaf(w, kA2.z, acc[10]); acc[11] = fmaf(w, kA2.w, acc[11]);
        acc[12] = fmaf(w, kA3.x, acc[12]); acc[13] = fmaf(w, kA3.y, acc[13]);
        acc[14] = fmaf(w, kA3.z, acc[14]); acc[15] = fmaf(w, kA3.w, acc[15]);
        dacc += w;

        mA = mB;
        cb ^= 1;
    }

    #pragma unroll
    for (int j = 0; j < 16; ++j) {
        #pragma unroll
        for (int off = 1; off <= 8; off <<= 1)
            acc[j] += __shfl_xor(acc[j], off, 64);
    }
    #pragma unroll
    for (int off = 1; off <= 8; off <<= 1)
        dacc += __shfl_xor(dacc, off, 64);

    if (l15 == 0) {
        float4 o0 = {acc[0],  acc[1],  acc[2],  acc[3]};
        float4 o1 = {acc[4],  acc[5],  acc[6],  acc[7]};
        float4 o2 = {acc[8],  acc[9],  acc[10], acc[11]};
        float4 o3 = {acc[12], acc[13], acc[14], acc[15]};
        *reinterpret_cast<float4*>(&part[wv][quad * 8 + 0])      = o0;
        *reinterpret_cast<float4*>(&part[wv][quad * 8 + 4])      = o1;
        *reinterpret_cast<float4*>(&part[wv][32 + quad * 8 + 0]) = o2;
        *reinterpret_cast<float4*>(&part[wv][32 + quad * 8 + 4]) = o3;
    }
    if (lane == 0) part[wv][64] = dacc;
    __syncthreads();

    if (tid < 64) {
        float s  = (part[0][tid] + part[1][tid]) + (part[2][tid] + part[3][tid]);
        float dn = (part[0][64]  + part[1][64])  + (part[2][64]  + part[3][64]);
        out[(size_t)b * D + tid] = s * __builtin_amdgcn_rcpf(dn);
    }
}

// ---------------- VERIFIED R9 path (final writer) ----------------
__global__ __launch_bounds__(256) void attn_pool_kernel(
        const float* __restrict__ keys,
        const int*   __restrict__ mask,
        const unsigned short* __restrict__ wkf,
        const float* __restrict__ wsum,
        const float* __restrict__ b1,
        const float* __restrict__ W2,
        const float* __restrict__ query,
        float*       __restrict__ out)
{
    __shared__ float qsh[4][64];
    __shared__ float part[4][68];

    const int tid  = threadIdx.x;
    const int wv   = tid >> 6;
    const int lane = tid & 63;
    const int quad = lane >> 4;
    const int l15  = lane & 15;

    const int b = blockIdx.x;

    qsh[wv][lane] = query[(size_t)b * D + lane];
    const int jq = lane & 31;
    const int kh = lane >> 5;
    float qac0 = kh ? 0.0f : b1[jq];
    float qac1 = 0.0f;
    #pragma unroll
    for (int k0 = 0; k0 < 32; k0 += 2) {
        int k = kh * 32 + k0;
        qac0 = fmaf(qsh[wv][k],     wsum[k * H + jq],       qac0);
        qac1 = fmaf(qsh[wv][k + 1], wsum[(k + 1) * H + jq], qac1);
    }
    float qac = qac0 + qac1;
    qac += __shfl_xor(qac, 32, 64);
    const float qa0 = __shfl(qac, l15, 64);
    const float qa1 = __shfl(qac, 16 + l15, 64);

    const short8* wf = reinterpret_cast<const short8*>(wkf);
    short8 bf0 = wf[0 * 64 + lane];
    short8 bf1 = wf[1 * 64 + lane];
    short8 bf2 = wf[2 * 64 + lane];
    short8 bf3 = wf[3 * 64 + lane];
    const float w20 = W2[l15];
    const float w21 = W2[16 + l15];

    const float4* krow = reinterpret_cast<const float4*>(keys + (size_t)b * (T * D));
    const int*    mrow = mask + (size_t)b * T;
    const int ib = quad * 2;

    float acc[16];
    #pragma unroll
    for (int j = 0; j < 16; ++j) acc[j] = 0.0f;
    float dacc = 0.0f;

    const int ntl = (wv == 0) ? 4 : 3;

    float4 kA0 = krow[(wv * 16 + l15) * 16 + ib + 0];
    float4 kA1 = krow[(wv * 16 + l15) * 16 + ib + 1];
    float4 kA2 = krow[(wv * 16 + l15) * 16 + 8 + ib + 0];
    float4 kA3 = krow[(wv * 16 + l15) * 16 + 8 + ib + 1];
    int    mA  = mrow[wv * 16 + l15];
    float4 kB0 = krow[((wv + 4) * 16 + l15) * 16 + ib + 0];
    float4 kB1 = krow[((wv + 4) * 16 + l15) * 16 + ib + 1];
    float4 kB2 = krow[((wv + 4) * 16 + l15) * 16 + 8 + ib + 0];
    float4 kB3 = krow[((wv + 4) * 16 + l15) * 16 + 8 + ib + 1];
    int    mB  = mrow[(wv + 4) * 16 + l15];

    #pragma unroll 1
    for (int it = 0; it < ntl; ++it) {
        const int tile = wv + it * 4;

        int tn  = (wv + (it + 2) * 4) * 16 + l15;
        int trn = (tn < T) ? tn : (T - 1);
        float4 kC0 = krow[trn * 16 + ib + 0];
        float4 kC1 = krow[trn * 16 + ib + 1];
        float4 kC2 = krow[trn * 16 + 8 + ib + 0];
        float4 kC3 = krow[trn * 16 + 8 + ib + 1];
        int    mC  = mrow[trn];

        short8 a0, a1;
        a0[0] = (short)bf16u(kA0.x); a0[1] = (short)bf16u(kA0.y);
        a0[2] = (short)bf16u(kA0.z); a0[3] = (short)bf16u(kA0.w);
        a0[4] = (short)bf16u(kA1.x); a0[5] = (short)bf16u(kA1.y);
        a0[6] = (short)bf16u(kA1.z); a0[7] = (short)bf16u(kA1.w);
        a1[0] = (short)bf16u(kA2.x); a1[1] = (short)bf16u(kA2.y);
        a1[2] = (short)bf16u(kA2.z); a1[3] = (short)bf16u(kA2.w);
        a1[4] = (short)bf16u(kA3.x); a1[5] = (short)bf16u(kA3.y);
        a1[6] = (short)bf16u(kA3.z); a1[7] = (short)bf16u(kA3.w);

        f32x4 c0 = {0.f, 0.f, 0.f, 0.f};
        f32x4 c1 = {0.f, 0.f, 0.f, 0.f};
        c0 = __builtin_amdgcn_mfma_f32_16x16x32_bf16(a0, bf0, c0, 0, 0, 0);
        c0 = __builtin_amdgcn_mfma_f32_16x16x32_bf16(a1, bf1, c0, 0, 0, 0);
        c1 = __builtin_amdgcn_mfma_f32_16x16x32_bf16(a0, bf2, c1, 0, 0, 0);
        c1 = __builtin_amdgcn_mfma_f32_16x16x32_bf16(a1, bf3, c1, 0, 0, 0);

        float p[4];
        #pragma unroll
        for (int r = 0; r < 4; ++r) {
            float x0 = c0[r] + qa0;
            float x1 = c1[r] + qa1;
            float s0 = __builtin_amdgcn_rcpf(1.0f + exp2f(-x0 * LOG2E));
            float s1 = __builtin_amdgcn_rcpf(1.0f + exp2f(-x1 * LOG2E));
            p[r] = fmaf(s0, w20, s1 * w21);
        }
        #pragma unroll
        for (int r = 0; r < 4; ++r) {
            #pragma unroll
            for (int off = 1; off <= 8; off <<= 1)
                p[r] += __shfl_xor(p[r], off, 64);
        }
        const int addr = (l15 >> 2) << 6;
        int q0 = __builtin_amdgcn_ds_bpermute(addr, __builtin_bit_cast(int, p[0]));
        int q1 = __builtin_amdgcn_ds_bpermute(addr, __builtin_bit_cast(int, p[1]));
        int q2 = __builtin_amdgcn_ds_bpermute(addr, __builtin_bit_cast(int, p[2]));
        int q3 = __builtin_amdgcn_ds_bpermute(addr, __builtin_bit_cast(int, p[3]));
        const int rsel = l15 & 3;
        int s01 = (rsel & 1) ? q1 : q0;
        int s23 = (rsel & 1) ? q3 : q2;
        float st = __builtin_bit_cast(float, (rsel & 2) ? s23 : s01);

        const int t = tile * 16 + l15;
        const float w = ((t < T) && (mA != 0)) ? exp2f((st - SOFF) * LOG2E) : 0.0f;

        acc[0]  = fmaf(w, kA0.x, acc[0]);  acc[1]  = fmaf(w, kA0.y, acc[1]);
        acc[2]  = fmaf(w, kA0.z, acc[2]);  acc[3]  = fmaf(w, kA0.w, acc[3]);
        acc[4]  = fmaf(w, kA1.x, acc[4]);  acc[5]  = fmaf(w, kA1.y, acc[5]);
        acc[6]  = fmaf(w, kA1.z, acc[6]);  acc[7]  = fmaf(w, kA1.w, acc[7]);
        acc[8]  = fmaf(w, kA2.x, acc[8]);  acc[9]  = fmaf(w, kA2.y, acc[9]);
        acc[10] = fmaf(w, kA2.z, acc[10]); acc[11] = fmaf(w, kA2.w, acc[11]);
        acc[12] = fmaf(w, kA3.x, acc[12]); acc[13] = fmaf(w, kA3.y, acc[13]);
        acc[14] = fmaf(w, kA3.z, acc[14]); acc[15] = fmaf(w, kA3.w, acc[15]);
        dacc += w;

        kA0 = kB0; kA1 = kB1; kA2 = kB2; kA3 = kB3; mA = mB;
        kB0 = kC0; kB1 = kC1; kB2 = kC2; kB3 = kC3; mB = mC;
    }

    #pragma unroll
    for (int j = 0; j < 16; ++j) {
        #pragma unroll
        for (int off = 1; off <= 8; off <<= 1)
            acc[j] += __shfl_xor(acc[j], off, 64);
    }
    #pragma unroll
    for (int off = 1; off <= 8; off <<= 1)
        dacc += __shfl_xor(dacc, off, 64);

    if (l15 == 0) {
        float4 o0 = {acc[0],  acc[1],  acc[2],  acc[3]};
        float4 o1 = {acc[4],  acc[5],  acc[6],  acc[7]};
        float4 o2 = {acc[8],  acc[9],  acc[10], acc[11]};
        float4 o3 = {acc[12], acc[13], acc[14], acc[15]};
        *reinterpret_cast<float4*>(&part[wv][quad * 8 + 0])      = o0;
        *reinterpret_cast<float4*>(&part[wv][quad * 8 + 4])      = o1;
        *reinterpret_cast<float4*>(&part[wv][32 + quad * 8 + 0]) = o2;
        *reinterpret_cast<float4*>(&part[wv][32 + quad * 8 + 4]) = o3;
    }
    if (lane == 0) part[wv][64] = dacc;
    __syncthreads();

    if (tid < 64) {
        float s  = (part[0][tid] + part[1][tid]) + (part[2][tid] + part[3][tid]);
        float dn = (part[0][64]  + part[1][64])  + (part[2][64]  + part[3][64]);
        out[(size_t)b * D + tid] = s * __builtin_amdgcn_rcpf(dn);
    }
}

extern "C" void kernel_launch(void* const* d_in, const int* in_sizes, int n_in,
                              void* d_out, int out_size, void* d_ws, size_t ws_size,
                              hipStream_t stream) {
    const float* query = (const float*)d_in[0];
    const float* keys  = (const float*)d_in[1];
    const int*   mask  = (const int*)d_in[2];
    const float* W1    = (const float*)d_in[3];
    const float* b1    = (const float*)d_in[4];
    const float* W2    = (const float*)d_in[5];
    // d_in[6] = b2: softmax-invariant, unused.

    float* ws = (float*)d_ws;
    float* wsum = ws;                                          // [64*32]
    unsigned short* wkf = (unsigned short*)(ws + 2048);        // 2048 bf16

    prep_kernel<<<16, 256, 0, stream>>>(W1, ws);
    // experimental first (timed via total-delta), verified kernel last (final out)
    attn_pool2_kernel<<<B, 256, 0, stream>>>(keys, mask, wkf, wsum, b1, W2,
                                             query, (float*)d_out);
    attn_pool_kernel<<<B, 256, 0, stream>>>(keys, mask, wkf, wsum, b1, W2,
                                            query, (float*)d_out);
}

// Round 7
// 304.670 us; speedup vs baseline: 1.1280x; 1.1280x over previous
//
#include <hip/hip_runtime.h>
#include <hip/hip_bf16.h>

// B=4096, T=200, D=64, H=32 attention pooling with score MLP.
// score(b,t) = W2 . sigmoid( qa[b] + k_t @ Wk ),  Wk = W1b - W1c   (b2 softmax-invariant)
// qa[b][j]  = b1[j] + q_b @ wsum[:,j],  wsum = W1a + W1c  (precomputed f32)
// Fixed-offset softmax: w_t = 2^((s_t-16)*log2e); masked -> 0.
//
// R11: R10's A/B measurement isolated the 5-round 2.6 TB/s plateau to the
// per-instruction GATHER SHAPE: stride-256B buffer_load_dwordx4 touches ~32
// scattered lines/instr (request-path bound); global_load_lds staging with
// lane-contiguous addresses (16 consecutive lines/instr) ran the same tile
// work at ~44 us (~4.7 TB/s). This round promotes the staged kernel to sole
// writer (downstream math is bit-identical to the verified R9 path):
//  - per tile: 4x global_load_lds (16B/lane) into wave-private LDS slab,
//    double-buffered; counted s_waitcnt vmcnt(4) (never 0 in the loop)
//  - XOR-swizzled granules, source-side permute + same involution on the
//    ds_read side (both-sides-or-neither, rule 21):
//      stage: dest granule sgi of row rl <- global granule (sgi&8)|((sgi^rl)&7)
//      read:  granule (2q+e) of row l15 at dest granule ((2q+e)^(l15&7)) (+8)
//  - mask/score/softmax/accum/reduce identical to R9 (verified R3/R4/R6-R9).

#define B 4096
#define T 200
#define D 64
#define H 32
#define LOG2E 1.44269504088896340736f
#define SOFF 16.0f
#define NTILE 13

typedef __attribute__((ext_vector_type(8))) short short8;   // 8 bf16 (MFMA A/B frag)
typedef __attribute__((ext_vector_type(4))) float f32x4;    // MFMA C/D frag

// ws float layout:
//   [0, 2048)       wsum[64][32] = W1a + W1c   (f32)
//   [2048, 3072)    wkf: 2048 bf16 B-fragments (1024 floats)

__global__ __launch_bounds__(256) void prep_kernel(
        const float* __restrict__ W1,     // [192,32]
        float*       __restrict__ ws)
{
    int n = blockIdx.x * 256 + threadIdx.x;
    if (blockIdx.x < 8) {                  // wsum = W1a + W1c
        int k = n >> 5;
        int j = n & 31;
        ws[n] = W1[k * H + j] + W1[(128 + k) * H + j];
    } else {                               // wkf B-fragments (layout verified R3/R4)
        int m = n - 2048;                  // 0..2047
        int e  = m & 7;
        int l  = (m >> 3) & 63;
        int fs = m >> 9;
        int ntile = fs >> 1, kstep = fs & 1;
        int k = kstep * 32 + (l >> 4) * 8 + e;
        int j = ntile * 16 + (l & 15);
        float v = W1[(64 + k) * H + j] - W1[(128 + k) * H + j];
        __hip_bfloat16 hv = __float2bfloat16(v);
        reinterpret_cast<unsigned short*>(ws + 2048)[m] =
            __builtin_bit_cast(unsigned short, hv);
    }
}

__device__ __forceinline__ unsigned short bf16u(float x) {
    __hip_bfloat16 h = __float2bfloat16(x);
    return __builtin_bit_cast(unsigned short, h);
}

__device__ __forceinline__ void gld16(const float* g, float* l) {
    __builtin_amdgcn_global_load_lds(
        (const __attribute__((address_space(1))) void*)g,
        (__attribute__((address_space(3))) void*)l, 16, 0, 0);
}

__global__ __launch_bounds__(256) void attn_pool_kernel(
        const float* __restrict__ keys,   // [B,T,D] fp32
        const int*   __restrict__ mask,   // [B,T]
        const unsigned short* __restrict__ wkf,
        const float* __restrict__ wsum,   // [64][32] f32
        const float* __restrict__ b1,     // [32]
        const float* __restrict__ W2,     // [32]
        const float* __restrict__ query,  // [B,1,D]
        float*       __restrict__ out)    // [B,1,D]
{
    __shared__ float kslab[4][2][1024];   // [wave][dbuf][16 rows x 64 f], swizzled
    __shared__ float qsh[4][64];
    __shared__ float part[4][68];

    const int tid  = threadIdx.x;
    const int wv   = tid >> 6;
    const int lane = tid & 63;
    const int quad = lane >> 4;
    const int l15  = lane & 15;

    const int b = blockIdx.x;

    // ---- qa[b][0..31] in-wave, f32 (identical to R9) ----
    qsh[wv][lane] = query[(size_t)b * D + lane];
    const int jq = lane & 31;
    const int kh = lane >> 5;
    float qac0 = kh ? 0.0f : b1[jq];
    float qac1 = 0.0f;
    #pragma unroll
    for (int k0 = 0; k0 < 32; k0 += 2) {
        int k = kh * 32 + k0;
        qac0 = fmaf(qsh[wv][k],     wsum[k * H + jq],       qac0);
        qac1 = fmaf(qsh[wv][k + 1], wsum[(k + 1) * H + jq], qac1);
    }
    float qac = qac0 + qac1;
    qac += __shfl_xor(qac, 32, 64);
    const float qa0 = __shfl(qac, l15, 64);
    const float qa1 = __shfl(qac, 16 + l15, 64);

    const short8* wf = reinterpret_cast<const short8*>(wkf);
    short8 bf0 = wf[0 * 64 + lane];
    short8 bf1 = wf[1 * 64 + lane];
    short8 bf2 = wf[2 * 64 + lane];
    short8 bf3 = wf[3 * 64 + lane];
    const float w20 = W2[l15];
    const float w21 = W2[16 + l15];

    const float* kbase = keys + (size_t)b * (T * D);
    const int*   mrow  = mask + (size_t)b * T;

    // staging lane mapping: instr i covers rows i*4..i*4+3 (1KB contiguous)
    const int srow = lane >> 4;           // row-within-group
    const int sgi  = lane & 15;           // dest granule (16B) within row

    float acc[16];
    #pragma unroll
    for (int j = 0; j < 16; ++j) acc[j] = 0.0f;
    float dacc = 0.0f;

    const int ntl = (wv == 0) ? 4 : 3;    // tiles wv, wv+4, wv+8 (+12 for wv 0)

    // prologue: stage tile wv into buf0 (rows <= 63 < T, no clamp)
    int mA = mrow[wv * 16 + l15];
    {
        const int tb = wv * 16;
        #pragma unroll
        for (int i = 0; i < 4; ++i) {
            int rl = i * 4 + srow;
            int sg = (sgi & 8) | ((sgi ^ rl) & 7);      // source-side swizzle
            gld16(kbase + (size_t)(tb + rl) * D + sg * 4, &kslab[wv][0][i * 256]);
        }
    }

    int cb = 0;
    #pragma unroll 1
    for (int it = 0; it < ntl; ++it) {
        const int tile = wv + it * 4;

        // stage tile+4 (row-clamped, uniform code) + its mask
        int tn  = (tile + 4) * 16 + l15;
        int trn = (tn < T) ? tn : (T - 1);
        int mB  = mrow[trn];
        {
            const int tb = (tile + 4) * 16;
            #pragma unroll
            for (int i = 0; i < 4; ++i) {
                int rl = i * 4 + srow;
                int rg = tb + rl; if (rg >= T) rg = T - 1;
                int sg = (sgi & 8) | ((sgi ^ rl) & 7);
                gld16(kbase + (size_t)rg * D + sg * 4, &kslab[wv][cb ^ 1][i * 256]);
            }
        }

        // drain current buffer's stage (4 newest = next stage stays in flight)
        asm volatile("s_waitcnt vmcnt(4)" ::: "memory");
        __builtin_amdgcn_sched_barrier(0);

        // swizzled fragment reads: same involution as the staging permute
        const float* sl = kslab[wv][cb];
        const int x   = l15 & 7;
        const int gi0 = ((2 * quad)     ^ x) & 7;
        const int gi1 = ((2 * quad + 1) ^ x) & 7;
        float4 kA0 = *reinterpret_cast<const float4*>(&sl[l15 * 64 + gi0 * 4]);
        float4 kA1 = *reinterpret_cast<const float4*>(&sl[l15 * 64 + gi1 * 4]);
        float4 kA2 = *reinterpret_cast<const float4*>(&sl[l15 * 64 + 32 + gi0 * 4]);
        float4 kA3 = *reinterpret_cast<const float4*>(&sl[l15 * 64 + 32 + gi1 * 4]);

        // ---- downstream identical to R9 (verified) ----
        short8 a0, a1;
        a0[0] = (short)bf16u(kA0.x); a0[1] = (short)bf16u(kA0.y);
        a0[2] = (short)bf16u(kA0.z); a0[3] = (short)bf16u(kA0.w);
        a0[4] = (short)bf16u(kA1.x); a0[5] = (short)bf16u(kA1.y);
        a0[6] = (short)bf16u(kA1.z); a0[7] = (short)bf16u(kA1.w);
        a1[0] = (short)bf16u(kA2.x); a1[1] = (short)bf16u(kA2.y);
        a1[2] = (short)bf16u(kA2.z); a1[3] = (short)bf16u(kA2.w);
        a1[4] = (short)bf16u(kA3.x); a1[5] = (short)bf16u(kA3.y);
        a1[6] = (short)bf16u(kA3.z); a1[7] = (short)bf16u(kA3.w);

        f32x4 c0 = {0.f, 0.f, 0.f, 0.f};
        f32x4 c1 = {0.f, 0.f, 0.f, 0.f};
        c0 = __builtin_amdgcn_mfma_f32_16x16x32_bf16(a0, bf0, c0, 0, 0, 0);
        c0 = __builtin_amdgcn_mfma_f32_16x16x32_bf16(a1, bf1, c0, 0, 0, 0);
        c1 = __builtin_amdgcn_mfma_f32_16x16x32_bf16(a0, bf2, c1, 0, 0, 0);
        c1 = __builtin_amdgcn_mfma_f32_16x16x32_bf16(a1, bf3, c1, 0, 0, 0);

        float p[4];
        #pragma unroll
        for (int r = 0; r < 4; ++r) {
            float x0 = c0[r] + qa0;
            float x1 = c1[r] + qa1;
            float s0 = __builtin_amdgcn_rcpf(1.0f + exp2f(-x0 * LOG2E));
            float s1 = __builtin_amdgcn_rcpf(1.0f + exp2f(-x1 * LOG2E));
            p[r] = fmaf(s0, w20, s1 * w21);
        }
        #pragma unroll
        for (int r = 0; r < 4; ++r) {
            #pragma unroll
            for (int off = 1; off <= 8; off <<= 1)
                p[r] += __shfl_xor(p[r], off, 64);      // reduce over 16 j-lanes
        }
        // route score[t'=l15] to the lane holding row t' (verified R4)
        const int addr = (l15 >> 2) << 6;
        int q0 = __builtin_amdgcn_ds_bpermute(addr, __builtin_bit_cast(int, p[0]));
        int q1 = __builtin_amdgcn_ds_bpermute(addr, __builtin_bit_cast(int, p[1]));
        int q2 = __builtin_amdgcn_ds_bpermute(addr, __builtin_bit_cast(int, p[2]));
        int q3 = __builtin_amdgcn_ds_bpermute(addr, __builtin_bit_cast(int, p[3]));
        const int rsel = l15 & 3;
        int s01 = (rsel & 1) ? q1 : q0;
        int s23 = (rsel & 1) ? q3 : q2;
        float st = __builtin_bit_cast(float, (rsel & 2) ? s23 : s01);

        const int t = tile * 16 + l15;
        const float w = ((t < T) && (mA != 0)) ? exp2f((st - SOFF) * LOG2E) : 0.0f;

        acc[0]  = fmaf(w, kA0.x, acc[0]);  acc[1]  = fmaf(w, kA0.y, acc[1]);
        acc[2]  = fmaf(w, kA0.z, acc[2]);  acc[3]  = fmaf(w, kA0.w, acc[3]);
        acc[4]  = fmaf(w, kA1.x, acc[4]);  acc[5]  = fmaf(w, kA1.y, acc[5]);
        acc[6]  = fmaf(w, kA1.z, acc[6]);  acc[7]  = fmaf(w, kA1.w, acc[7]);
        acc[8]  = fmaf(w, kA2.x, acc[8]);  acc[9]  = fmaf(w, kA2.y, acc[9]);
        acc[10] = fmaf(w, kA2.z, acc[10]); acc[11] = fmaf(w, kA2.w, acc[11]);
        acc[12] = fmaf(w, kA3.x, acc[12]); acc[13] = fmaf(w, kA3.y, acc[13]);
        acc[14] = fmaf(w, kA3.z, acc[14]); acc[15] = fmaf(w, kA3.w, acc[15]);
        dacc += w;

        mA = mB;
        cb ^= 1;
    }

    // intra-wave reduction over the 16 t-lanes
    #pragma unroll
    for (int j = 0; j < 16; ++j) {
        #pragma unroll
        for (int off = 1; off <= 8; off <<= 1)
            acc[j] += __shfl_xor(acc[j], off, 64);
    }
    #pragma unroll
    for (int off = 1; off <= 8; off <<= 1)
        dacc += __shfl_xor(dacc, off, 64);

    // write this wave's partial (cols per quad) to LDS
    if (l15 == 0) {
        float4 o0 = {acc[0],  acc[1],  acc[2],  acc[3]};
        float4 o1 = {acc[4],  acc[5],  acc[6],  acc[7]};
        float4 o2 = {acc[8],  acc[9],  acc[10], acc[11]};
        float4 o3 = {acc[12], acc[13], acc[14], acc[15]};
        *reinterpret_cast<float4*>(&part[wv][quad * 8 + 0])      = o0;
        *reinterpret_cast<float4*>(&part[wv][quad * 8 + 4])      = o1;
        *reinterpret_cast<float4*>(&part[wv][32 + quad * 8 + 0]) = o2;
        *reinterpret_cast<float4*>(&part[wv][32 + quad * 8 + 4]) = o3;
    }
    if (lane == 0) part[wv][64] = dacc;
    __syncthreads();

    // combine the 4 wave partials and write out (64 threads: 64 cols)
    if (tid < 64) {
        float s  = (part[0][tid] + part[1][tid]) + (part[2][tid] + part[3][tid]);
        float dn = (part[0][64]  + part[1][64])  + (part[2][64]  + part[3][64]);
        out[(size_t)b * D + tid] = s * __builtin_amdgcn_rcpf(dn);
    }
}

extern "C" void kernel_launch(void* const* d_in, const int* in_sizes, int n_in,
                              void* d_out, int out_size, void* d_ws, size_t ws_size,
                              hipStream_t stream) {
    const float* query = (const float*)d_in[0];
    const float* keys  = (const float*)d_in[1];
    const int*   mask  = (const int*)d_in[2];
    const float* W1    = (const float*)d_in[3];
    const float* b1    = (const float*)d_in[4];
    const float* W2    = (const float*)d_in[5];
    // d_in[6] = b2: softmax-invariant, unused.

    float* ws = (float*)d_ws;
    float* wsum = ws;                                          // [64*32]
    unsigned short* wkf = (unsigned short*)(ws + 2048);        // 2048 bf16

    prep_kernel<<<16, 256, 0, stream>>>(W1, ws);
    attn_pool_kernel<<<B, 256, 0, stream>>>(keys, mask, wkf, wsum, b1, W2,
                                            query, (float*)d_out);
}

// Round 8
// 296.696 us; speedup vs baseline: 1.1584x; 1.0269x over previous
//
#include <hip/hip_runtime.h>
#include <hip/hip_bf16.h>

// B=4096, T=200, D=64, H=32 attention pooling with score MLP.
// score(b,t) = W2 . sigmoid( qa[b] + k_t @ Wk ),  Wk = W1b - W1c   (b2 softmax-invariant)
// qa[b][j]  = b1[j] + q_b @ wsum[:,j],  wsum = W1a + W1c  (precomputed f32)
// Fixed-offset softmax: w_t = 2^((s_t-16)*log2e); masked -> 0.
//
// R12: R10/R11 A/B resolved the ledger: cold attn = 80-85us (2.6 TB/s) for SIX
// structures across two disjoint load paths; same kernel warm = 39us (5.3 TB/s).
// -> cold penalty is environmental: the harness's 800MB d_ws poison leaves ~256MB
// of DIRTY lines in L3; our 206MB key read allocates, forcing ~1 writeback per
// allocated line -> ~410MB effective traffic in the attn window. Fix: keys/mask
// are zero-reuse streams -> NON-TEMPORAL loads (nt cache policy, no allocate) so
// reads stop evicting dirty poison lines. Base = R9 structure (best total:
// block-per-b, 4-wave interleaved tiles, 2-deep register prefetch); ONLY the
// keys/mask loads change to __builtin_nontemporal_load. All score/softmax/accum
// machinery byte-identical (verified R3/R4, R6-R11).

#define B 4096
#define T 200
#define D 64
#define H 32
#define LOG2E 1.44269504088896340736f
#define SOFF 16.0f
#define NTILE 13

typedef __attribute__((ext_vector_type(8))) short short8;   // 8 bf16 (MFMA A/B frag)
typedef __attribute__((ext_vector_type(4))) float f32x4;    // MFMA C/D frag

// ws float layout:
//   [0, 2048)       wsum[64][32] = W1a + W1c   (f32)
//   [2048, 3072)    wkf: 2048 bf16 B-fragments (1024 floats)

__global__ __launch_bounds__(256) void prep_kernel(
        const float* __restrict__ W1,     // [192,32]
        float*       __restrict__ ws)
{
    int n = blockIdx.x * 256 + threadIdx.x;
    if (blockIdx.x < 8) {                  // wsum = W1a + W1c
        int k = n >> 5;
        int j = n & 31;
        ws[n] = W1[k * H + j] + W1[(128 + k) * H + j];
    } else {                               // wkf B-fragments (layout verified R3/R4)
        int m = n - 2048;                  // 0..2047
        int e  = m & 7;
        int l  = (m >> 3) & 63;
        int fs = m >> 9;
        int ntile = fs >> 1, kstep = fs & 1;
        int k = kstep * 32 + (l >> 4) * 8 + e;
        int j = ntile * 16 + (l & 15);
        float v = W1[(64 + k) * H + j] - W1[(128 + k) * H + j];
        __hip_bfloat16 hv = __float2bfloat16(v);
        reinterpret_cast<unsigned short*>(ws + 2048)[m] =
            __builtin_bit_cast(unsigned short, hv);
    }
}

__device__ __forceinline__ unsigned short bf16u(float x) {
    __hip_bfloat16 h = __float2bfloat16(x);
    return __builtin_bit_cast(unsigned short, h);
}

// non-temporal 16B load (nt policy: no L2/L3 allocate -> no dirty-line eviction)
__device__ __forceinline__ float4 ntld4(const float4* p) {
    f32x4 v = __builtin_nontemporal_load(reinterpret_cast<const f32x4*>(p));
    return __builtin_bit_cast(float4, v);
}
__device__ __forceinline__ int ntldi(const int* p) {
    return __builtin_nontemporal_load(p);
}

__global__ __launch_bounds__(256) void attn_pool_kernel(
        const float* __restrict__ keys,   // [B,T,D] fp32
        const int*   __restrict__ mask,   // [B,T]
        const unsigned short* __restrict__ wkf, // 2048 bf16 B-fragments
        const float* __restrict__ wsum,   // [64][32] f32
        const float* __restrict__ b1,     // [32]
        const float* __restrict__ W2,     // [32]
        const float* __restrict__ query,  // [B,1,D]
        float*       __restrict__ out)    // [B,1,D]
{
    __shared__ float qsh[4][64];
    __shared__ float part[4][68];         // [wave][64 cols + den]

    const int tid  = threadIdx.x;
    const int wv   = tid >> 6;
    const int lane = tid & 63;
    const int quad = lane >> 4;
    const int l15  = lane & 15;

    const int b = blockIdx.x;             // one block per batch row

    // ---- qa[b][0..31] computed in-wave, f32 ----
    qsh[wv][lane] = query[(size_t)b * D + lane];        // stage query row
    const int jq = lane & 31;
    const int kh = lane >> 5;                           // k-half per lane group
    float qac0 = kh ? 0.0f : b1[jq];
    float qac1 = 0.0f;
    #pragma unroll
    for (int k0 = 0; k0 < 32; k0 += 2) {
        int k = kh * 32 + k0;
        qac0 = fmaf(qsh[wv][k],     wsum[k * H + jq],       qac0);
        qac1 = fmaf(qsh[wv][k + 1], wsum[(k + 1) * H + jq], qac1);
    }
    float qac = qac0 + qac1;
    qac += __shfl_xor(qac, 32, 64);                     // combine k-halves
    const float qa0 = __shfl(qac, l15, 64);             // qa[l15]
    const float qa1 = __shfl(qac, 16 + l15, 64);        // qa[16+l15]

    // ---- Wk B-fragments (L2-broadcast) + W2 ----
    const short8* wf = reinterpret_cast<const short8*>(wkf);
    short8 bf0 = wf[0 * 64 + lane];
    short8 bf1 = wf[1 * 64 + lane];
    short8 bf2 = wf[2 * 64 + lane];
    short8 bf3 = wf[3 * 64 + lane];
    const float w20 = W2[l15];
    const float w21 = W2[16 + l15];

    const float4* krow = reinterpret_cast<const float4*>(keys + (size_t)b * (T * D));
    const int*    mrow = mask + (size_t)b * T;
    const int ib = quad * 2;

    // register accumulators: lane covers cols {quad*8..+7} u {32+quad*8..+7}
    float acc[16];
    #pragma unroll
    for (int j = 0; j < 16; ++j) acc[j] = 0.0f;
    float dacc = 0.0f;

    // interleaved tile assignment: wave wv takes tiles wv, wv+4, wv+8 (+12 for wv=0)
    const int ntl = (wv == 0) ? 4 : 3;

    // 2-deep prefetch: tiles wv (A) and wv+4 (B) in flight before the loop.
    // t(A) = wv*16+l15 <= 63, t(B) = (wv+4)*16+l15 <= 127 -> both < T, no clamp.
    float4 kA0 = ntld4(&krow[(wv * 16 + l15) * 16 + ib + 0]);
    float4 kA1 = ntld4(&krow[(wv * 16 + l15) * 16 + ib + 1]);
    float4 kA2 = ntld4(&krow[(wv * 16 + l15) * 16 + 8 + ib + 0]);
    float4 kA3 = ntld4(&krow[(wv * 16 + l15) * 16 + 8 + ib + 1]);
    int    mA  = ntldi(&mrow[wv * 16 + l15]);
    float4 kB0 = ntld4(&krow[((wv + 4) * 16 + l15) * 16 + ib + 0]);
    float4 kB1 = ntld4(&krow[((wv + 4) * 16 + l15) * 16 + ib + 1]);
    float4 kB2 = ntld4(&krow[((wv + 4) * 16 + l15) * 16 + 8 + ib + 0]);
    float4 kB3 = ntld4(&krow[((wv + 4) * 16 + l15) * 16 + 8 + ib + 1]);
    int    mB  = ntldi(&mrow[(wv + 4) * 16 + l15]);

    #pragma unroll 1
    for (int it = 0; it < ntl; ++it) {
        const int tile = wv + it * 4;

        // issue prefetch for tile+2 FIRST, unconditional, address-clamped
        // (last 2 iterations re-read row T-1: 256B, harmless)
        int tn  = (wv + (it + 2) * 4) * 16 + l15;
        int trn = (tn < T) ? tn : (T - 1);
        float4 kC0 = ntld4(&krow[trn * 16 + ib + 0]);
        float4 kC1 = ntld4(&krow[trn * 16 + ib + 1]);
        float4 kC2 = ntld4(&krow[trn * 16 + 8 + ib + 0]);
        float4 kC3 = ntld4(&krow[trn * 16 + 8 + ib + 1]);
        int    mC  = ntldi(&mrow[trn]);

        // bf16 A-fragments: A[m=l15][k=quad*8+e], second frag k+32
        short8 a0, a1;
        a0[0] = (short)bf16u(kA0.x); a0[1] = (short)bf16u(kA0.y);
        a0[2] = (short)bf16u(kA0.z); a0[3] = (short)bf16u(kA0.w);
        a0[4] = (short)bf16u(kA1.x); a0[5] = (short)bf16u(kA1.y);
        a0[6] = (short)bf16u(kA1.z); a0[7] = (short)bf16u(kA1.w);
        a1[0] = (short)bf16u(kA2.x); a1[1] = (short)bf16u(kA2.y);
        a1[2] = (short)bf16u(kA2.z); a1[3] = (short)bf16u(kA2.w);
        a1[4] = (short)bf16u(kA3.x); a1[5] = (short)bf16u(kA3.y);
        a1[6] = (short)bf16u(kA3.z); a1[7] = (short)bf16u(kA3.w);

        f32x4 c0 = {0.f, 0.f, 0.f, 0.f};
        f32x4 c1 = {0.f, 0.f, 0.f, 0.f};
        c0 = __builtin_amdgcn_mfma_f32_16x16x32_bf16(a0, bf0, c0, 0, 0, 0);
        c0 = __builtin_amdgcn_mfma_f32_16x16x32_bf16(a1, bf1, c0, 0, 0, 0);
        c1 = __builtin_amdgcn_mfma_f32_16x16x32_bf16(a0, bf2, c1, 0, 0, 0);
        c1 = __builtin_amdgcn_mfma_f32_16x16x32_bf16(a1, bf3, c1, 0, 0, 0);

        // sigmoid + W2 contraction; D layout: row t' = quad*4+r, col j = l15
        float p[4];
        #pragma unroll
        for (int r = 0; r < 4; ++r) {
            float x0 = c0[r] + qa0;
            float x1 = c1[r] + qa1;
            float s0 = __builtin_amdgcn_rcpf(1.0f + exp2f(-x0 * LOG2E));
            float s1 = __builtin_amdgcn_rcpf(1.0f + exp2f(-x1 * LOG2E));
            p[r] = fmaf(s0, w20, s1 * w21);
        }
        #pragma unroll
        for (int r = 0; r < 4; ++r) {
            #pragma unroll
            for (int off = 1; off <= 8; off <<= 1)
                p[r] += __shfl_xor(p[r], off, 64);      // reduce over 16 j-lanes
        }
        // route score[t'=l15] to the lane holding row t' (verified R4)
        const int addr = (l15 >> 2) << 6;
        int q0 = __builtin_amdgcn_ds_bpermute(addr, __builtin_bit_cast(int, p[0]));
        int q1 = __builtin_amdgcn_ds_bpermute(addr, __builtin_bit_cast(int, p[1]));
        int q2 = __builtin_amdgcn_ds_bpermute(addr, __builtin_bit_cast(int, p[2]));
        int q3 = __builtin_amdgcn_ds_bpermute(addr, __builtin_bit_cast(int, p[3]));
        const int rsel = l15 & 3;
        int s01 = (rsel & 1) ? q1 : q0;
        int s23 = (rsel & 1) ? q3 : q2;
        float st = __builtin_bit_cast(float, (rsel & 2) ? s23 : s01);

        const int t = tile * 16 + l15;
        const float w = ((t < T) && (mA != 0)) ? exp2f((st - SOFF) * LOG2E) : 0.0f;

        // register accumulation
        acc[0]  = fmaf(w, kA0.x, acc[0]);  acc[1]  = fmaf(w, kA0.y, acc[1]);
        acc[2]  = fmaf(w, kA0.z, acc[2]);  acc[3]  = fmaf(w, kA0.w, acc[3]);
        acc[4]  = fmaf(w, kA1.x, acc[4]);  acc[5]  = fmaf(w, kA1.y, acc[5]);
        acc[6]  = fmaf(w, kA1.z, acc[6]);  acc[7]  = fmaf(w, kA1.w, acc[7]);
        acc[8]  = fmaf(w, kA2.x, acc[8]);  acc[9]  = fmaf(w, kA2.y, acc[9]);
        acc[10] = fmaf(w, kA2.z, acc[10]); acc[11] = fmaf(w, kA2.w, acc[11]);
        acc[12] = fmaf(w, kA3.x, acc[12]); acc[13] = fmaf(w, kA3.y, acc[13]);
        acc[14] = fmaf(w, kA3.z, acc[14]); acc[15] = fmaf(w, kA3.w, acc[15]);
        dacc += w;

        // rotate the 3-buffer pipeline
        kA0 = kB0; kA1 = kB1; kA2 = kB2; kA3 = kB3; mA = mB;
        kB0 = kC0; kB1 = kC1; kB2 = kC2; kB3 = kC3; mB = mC;
    }

    // intra-wave reduction over the 16 t-lanes
    #pragma unroll
    for (int j = 0; j < 16; ++j) {
        #pragma unroll
        for (int off = 1; off <= 8; off <<= 1)
            acc[j] += __shfl_xor(acc[j], off, 64);
    }
    #pragma unroll
    for (int off = 1; off <= 8; off <<= 1)
        dacc += __shfl_xor(dacc, off, 64);

    // write this wave's partial (cols per quad) to LDS
    if (l15 == 0) {
        float4 o0 = {acc[0],  acc[1],  acc[2],  acc[3]};
        float4 o1 = {acc[4],  acc[5],  acc[6],  acc[7]};
        float4 o2 = {acc[8],  acc[9],  acc[10], acc[11]};
        float4 o3 = {acc[12], acc[13], acc[14], acc[15]};
        *reinterpret_cast<float4*>(&part[wv][quad * 8 + 0])      = o0;
        *reinterpret_cast<float4*>(&part[wv][quad * 8 + 4])      = o1;
        *reinterpret_cast<float4*>(&part[wv][32 + quad * 8 + 0]) = o2;
        *reinterpret_cast<float4*>(&part[wv][32 + quad * 8 + 4]) = o3;
    }
    if (lane == 0) part[wv][64] = dacc;
    __syncthreads();

    // combine the 4 wave partials and write out (64 threads: 64 cols)
    if (tid < 64) {
        float s  = (part[0][tid] + part[1][tid]) + (part[2][tid] + part[3][tid]);
        float dn = (part[0][64]  + part[1][64])  + (part[2][64]  + part[3][64]);
        out[(size_t)b * D + tid] = s * __builtin_amdgcn_rcpf(dn);
    }
}

extern "C" void kernel_launch(void* const* d_in, const int* in_sizes, int n_in,
                              void* d_out, int out_size, void* d_ws, size_t ws_size,
                              hipStream_t stream) {
    const float* query = (const float*)d_in[0];
    const float* keys  = (const float*)d_in[1];
    const int*   mask  = (const int*)d_in[2];
    const float* W1    = (const float*)d_in[3];
    const float* b1    = (const float*)d_in[4];
    const float* W2    = (const float*)d_in[5];
    // d_in[6] = b2: softmax-invariant, unused.

    float* ws = (float*)d_ws;
    float* wsum = ws;                                          // [64*32]
    unsigned short* wkf = (unsigned short*)(ws + 2048);        // 2048 bf16

    prep_kernel<<<16, 256, 0, stream>>>(W1, ws);
    attn_pool_kernel<<<B, 256, 0, stream>>>(keys, mask, wkf, wsum, b1, W2,
                                            query, (float*)d_out);
}